// Round 12
// baseline (234.672 us; speedup 1.0000x reference)
//
#include <hip/hip_runtime.h>
#include <hip/hip_bf16.h>
#include <hip/hip_cooperative_groups.h>
#include <math.h>

namespace cg = cooperative_groups;

#define B_TOTAL 262144
#define NHEADS  30
#define D1      128
#define D2      64
#define DH      32
#define BLK     256
#define GRID_MAX 1024
#define NBLK_IN (B_TOTAL / BLK)            // 1024 input chunks (256 samples each)
#define SB      128                        // slots per main tile
#define MAX_MB  (B_TOTAL / SB + NHEADS)    // 2078 main tiles

#define TANH_K  2.885390081777927f         // 2/ln2: tanh(v)=1-2/(exp2(K v)+1)

typedef __attribute__((ext_vector_type(8))) __bf16 bf16x8;
typedef __attribute__((ext_vector_type(4))) float  f32x4;

// ---------------- ws layout (bytes) ----------------
// 0        counts[30] u32
// 128      starts[30] u32            (slot units, multiples of 128)
// 512      block_head[MAX_MB] i32
// 16384    block_counts[30][1024] u32  (transposed)
// 139264   block_off[30][1024] u32     (transposed)
// 270336   perm[MAX_MB*SB] i32       (no init; guarded by counts)
// 1349632  inv[B_TOTAL] i32          (fallback path only)
// 2400256  temp[MAX_MB*SB*2] f32     (fallback path only)
// 4558848  W2f  bf16[8192]           (fragment-ordered, pre-scaled by TANH_K)
// 4575232  HW1f bf16[30*2048]        (fragment-ordered, pre-scaled by TANH_K)
// 4700160  hids u8[B_TOTAL]

__device__ __forceinline__ int head_id(int nn, int ll, int mm) {
    return (nn - 1) * nn * (2 * nn - 1) / 6 + ll * ll + (mm + ll);
}

__device__ __forceinline__ float tanh_pre(float u) {
    float e = __builtin_amdgcn_exp2f(u);
    return 1.0f - 2.0f * __builtin_amdgcn_rcpf(e + 1.0f);
}

// ---- shared phase bodies (device inline) ----

__device__ __forceinline__ void hist_body(int cb, int t,
    const int* __restrict__ n, const int* __restrict__ l, const int* __restrict__ m,
    unsigned* __restrict__ block_counts, unsigned char* __restrict__ hids,
    const float* __restrict__ W2, const float* __restrict__ HW1,
    __bf16* __restrict__ W2f, __bf16* __restrict__ HW1f,
    unsigned* lh)
{
    if (t < NHEADS) lh[t] = 0u;
    __syncthreads();
    int i = cb * BLK + t;
    int hid = head_id(n[i], l[i], m[i]);
    hids[i] = (unsigned char)hid;
    atomicAdd(&lh[hid], 1u);

    if (cb < 272) {                          // one-time weight conversion (pre-scaled)
        int idx = cb * BLK + t;
        if (idx < 8192) {
            int jj = idx & 7, ln = (idx >> 3) & 63, nt = (idx >> 9) & 3, kt = (idx >> 11) & 3;
            int k = kt * 32 + (ln >> 4) * 8 + jj;
            int c = nt * 16 + (ln & 15);
            W2f[idx] = (__bf16)(W2[k * D2 + c] * TANH_K);
        } else {
            int id2 = idx - 8192;            // < 61440
            int jj = id2 & 7, ln = (id2 >> 3) & 63;
            int nt2 = (id2 >> 9) & 1, kt2 = (id2 >> 10) & 1, h = id2 >> 11;
            int k = kt2 * 32 + (ln >> 4) * 8 + jj;
            int c = nt2 * 16 + (ln & 15);
            HW1f[h * 2048 + ((kt2 * 2 + nt2) * 64 + ln) * 8 + jj] =
                (__bf16)(HW1[h * (D2 * DH) + k * DH + c] * TANH_K);
        }
    }
    __syncthreads();
    if (t < NHEADS) block_counts[t * NBLK_IN + cb] = lh[t];   // transposed
}

__device__ __forceinline__ void scan_body(int bid, int t,
    const unsigned* __restrict__ block_counts,
    unsigned* __restrict__ block_off, unsigned* __restrict__ counts,
    unsigned* __restrict__ starts, int* __restrict__ block_head,
    unsigned* wsum, unsigned* stotal, unsigned* cumblk)
{
    int lane = t & 63, wv = t >> 6;
    if (bid < NHEADS) {
        int h = bid;
        uint4 v = reinterpret_cast<const uint4*>(block_counts + h * NBLK_IN)[t];
        unsigned tsum = v.x + v.y + v.z + v.w;
        unsigned s = tsum;
        #pragma unroll
        for (int d = 1; d < 64; d <<= 1) {
            unsigned u = __shfl_up(s, d, 64);
            if (lane >= d) s += u;
        }
        if (lane == 63) wsum[wv] = s;
        __syncthreads();
        unsigned woff = 0;
        #pragma unroll
        for (int w = 0; w < 3; ++w) woff += (w < wv) ? wsum[w] : 0u;
        unsigned ex = woff + s - tsum;
        uint4 o;
        o.x = ex;
        o.y = ex + v.x;
        o.z = ex + v.x + v.y;
        o.w = ex + v.x + v.y + v.z;
        reinterpret_cast<uint4*>(block_off + h * NBLK_IN)[t] = o;
    } else if (bid == NHEADS) {
        for (int hh = wv; hh < NHEADS; hh += 4) {
            const uint4* p = reinterpret_cast<const uint4*>(block_counts + hh * NBLK_IN);
            unsigned sum = 0;
            #pragma unroll
            for (int c = 0; c < 4; ++c) {
                uint4 v = p[lane + c * 64];
                sum += v.x + v.y + v.z + v.w;
            }
            #pragma unroll
            for (int d = 32; d >= 1; d >>= 1) sum += __shfl_down(sum, d, 64);
            if (lane == 0) { stotal[hh] = sum; counts[hh] = sum; }
        }
        __syncthreads();
        if (t == 0) {
            unsigned tb = 0;
            for (int hh = 0; hh < NHEADS; ++hh) {
                starts[hh] = tb * SB;
                cumblk[hh] = tb;
                tb += (stotal[hh] + SB - 1) / SB;
            }
            cumblk[NHEADS] = tb;
        }
        __syncthreads();
        unsigned tb = cumblk[NHEADS];
        for (int b = t; b < MAX_MB; b += BLK) {
            int hh = -1;
            if ((unsigned)b < tb) {
                hh = 0;
                while (cumblk[hh + 1] <= (unsigned)b) ++hh;
            }
            block_head[b] = hh;
        }
    }
}

__device__ __forceinline__ void scatter_body(int cb, int t,
    const unsigned char* __restrict__ hids,
    const unsigned* __restrict__ starts, const unsigned* __restrict__ block_off,
    int* __restrict__ perm, int* __restrict__ inv, bool write_inv,
    unsigned* lcur)
{
    if (t < NHEADS) lcur[t] = 0u;
    __syncthreads();
    int i = cb * BLK + t;
    int hid = hids[i];
    unsigned rank = atomicAdd(&lcur[hid], 1u);
    unsigned pos = starts[hid] + block_off[hid * NBLK_IN + cb] + rank;
    perm[pos] = i;
    if (write_inv) inv[i] = (int)pos;
    __syncthreads();
}

// per-tile MLP compute; sw = prescaled W1|W1'|b1 (LDS), Tw = this wave's 32x64 tile
__device__ __forceinline__ void tile_compute(
    float x0, float x1, int h, int lane,
    const float* __restrict__ b2, const float* __restrict__ Hb1,
    const float* __restrict__ HW2, const float* __restrict__ Hb2,
    const __bf16* __restrict__ W2f, const __bf16* __restrict__ HW1f,
    const float* __restrict__ sw, __bf16* __restrict__ Tw,
    float& o0r, float& o1r)
{
    int kgrp = lane >> 4;
    int lid  = lane & 15;
    int row  = lane & 31;

    float xs0[2], xs1[2];
    #pragma unroll
    for (int tm = 0; tm < 2; ++tm) {
        int src = tm * 16 + lid;
        xs0[tm] = __shfl(x0, src, 64);
        xs1[tm] = __shfl(x1, src, 64);
    }

    // layer 2 GEMM: [32x128]x[128x64] per wave, acc init = K*b2
    f32x4 acc2[2][4];
    #pragma unroll
    for (int nt = 0; nt < 4; ++nt) {
        float bv = b2[nt * 16 + lid] * TANH_K;
        f32x4 c4 = {bv, bv, bv, bv};
        acc2[0][nt] = c4;
        acc2[1][nt] = c4;
    }

    #pragma unroll
    for (int kt = 0; kt < 4; ++kt) {
        int jb = kt * 32 + kgrp * 8;
        float4 w0a = *(const float4*)&sw[jb];
        float4 w0b = *(const float4*)&sw[jb + 4];
        float4 w1a = *(const float4*)&sw[D1 + jb];
        float4 w1b = *(const float4*)&sw[D1 + jb + 4];
        float4 bba = *(const float4*)&sw[2 * D1 + jb];
        float4 bbb = *(const float4*)&sw[2 * D1 + jb + 4];
        float w0[8] = {w0a.x, w0a.y, w0a.z, w0a.w, w0b.x, w0b.y, w0b.z, w0b.w};
        float w1[8] = {w1a.x, w1a.y, w1a.z, w1a.w, w1b.x, w1b.y, w1b.z, w1b.w};
        float bb[8] = {bba.x, bba.y, bba.z, bba.w, bbb.x, bbb.y, bbb.z, bbb.w};
        bf16x8 a1[2];
        #pragma unroll
        for (int tm = 0; tm < 2; ++tm)
            #pragma unroll
            for (int jj = 0; jj < 8; ++jj) {
                float v = tanh_pre(fmaf(xs1[tm], w1[jj], fmaf(xs0[tm], w0[jj], bb[jj])));
                a1[tm][jj] = (__bf16)v;
            }
        #pragma unroll
        for (int nt = 0; nt < 4; ++nt) {
            bf16x8 bfr = *reinterpret_cast<const bf16x8*>(W2f + ((kt * 4 + nt) * 64 + lane) * 8);
            #pragma unroll
            for (int tm = 0; tm < 2; ++tm)
                acc2[tm][nt] = __builtin_amdgcn_mfma_f32_16x16x32_bf16(a1[tm], bfr, acc2[tm][nt], 0, 0, 0);
        }
    }

    // h2 = tanh(acc2) -> Tw cols 0..63 (chunk = (c>>3)^(r&7))
    #pragma unroll
    for (int tm = 0; tm < 2; ++tm)
        #pragma unroll
        for (int nt = 0; nt < 4; ++nt)
            #pragma unroll
            for (int rg = 0; rg < 4; ++rg) {
                int r = tm * 16 + kgrp * 4 + rg;
                int c = nt * 16 + lid;
                int chunk = (c >> 3) ^ (r & 7);
                Tw[r * 64 + chunk * 8 + (c & 7)] = (__bf16)tanh_pre(acc2[tm][nt][rg]);
            }

    // head layer 1 GEMM: [32x64]x[64x32], acc init = K*Hb1
    f32x4 acc3[2][2];
    #pragma unroll
    for (int nt = 0; nt < 2; ++nt) {
        float bv = Hb1[h * DH + nt * 16 + lid] * TANH_K;
        f32x4 c4 = {bv, bv, bv, bv};
        acc3[0][nt] = c4;
        acc3[1][nt] = c4;
    }
    #pragma unroll
    for (int kt2 = 0; kt2 < 2; ++kt2) {
        #pragma unroll
        for (int tm = 0; tm < 2; ++tm) {
            int r = tm * 16 + lid;
            int chunk = (kt2 * 4 + kgrp) ^ (r & 7);
            bf16x8 a2v = *reinterpret_cast<const bf16x8*>(&Tw[r * 64 + chunk * 8]);
            #pragma unroll
            for (int nt3 = 0; nt3 < 2; ++nt3) {
                bf16x8 bfr = *reinterpret_cast<const bf16x8*>(HW1f + h * 2048 + ((kt2 * 2 + nt3) * 64 + lane) * 8);
                acc3[tm][nt3] = __builtin_amdgcn_mfma_f32_16x16x32_bf16(a2v, bfr, acc3[tm][nt3], 0, 0, 0);
            }
        }
    }

    // z = tanh(acc3) -> Tw cols 32..63 (h2 reads precede in wave program order)
    #pragma unroll
    for (int tm = 0; tm < 2; ++tm)
        #pragma unroll
        for (int nt3 = 0; nt3 < 2; ++nt3)
            #pragma unroll
            for (int rg = 0; rg < 4; ++rg) {
                int r = tm * 16 + kgrp * 4 + rg;
                int c = 32 + nt3 * 16 + lid;
                int chunk = (c >> 3) ^ (r & 7);
                Tw[r * 64 + chunk * 8 + (c & 7)] = (__bf16)tanh_pre(acc3[tm][nt3][rg]);
            }

    // head layer 2 (VALU, uniform s_load weights); lanes 32-63 duplicate
    const float* hw2 = HW2 + h * DH * 2;
    float o0 = Hb2[h * 2], o1 = Hb2[h * 2 + 1];
    #pragma unroll
    for (int i4 = 0; i4 < 4; ++i4) {
        int chunk = (4 + i4) ^ (row & 7);
        bf16x8 zz = *reinterpret_cast<const bf16x8*>(&Tw[row * 64 + chunk * 8]);
        #pragma unroll
        for (int jj = 0; jj < 8; ++jj) {
            float zv = (float)zz[jj];
            int j = i4 * 8 + jj;
            o0 = fmaf(zv, hw2[2 * j], o0);
            o1 = fmaf(zv, hw2[2 * j + 1], o1);
        }
    }
    o0r = o0;
    o1r = o1;
}

// ================= cooperative fused kernel =================
__global__ __launch_bounds__(BLK, 4) void k_fused(
    const float* __restrict__ x,
    const int* __restrict__ n, const int* __restrict__ l, const int* __restrict__ m,
    const float* __restrict__ W1, const float* __restrict__ b1,
    const float* __restrict__ W2, const float* __restrict__ b2,
    const float* __restrict__ HW1, const float* __restrict__ Hb1,
    const float* __restrict__ HW2, const float* __restrict__ Hb2,
    unsigned* __restrict__ counts, unsigned* __restrict__ starts,
    int* __restrict__ block_head,
    unsigned* __restrict__ block_counts, unsigned* __restrict__ block_off,
    int* __restrict__ perm,
    __bf16* __restrict__ W2f, __bf16* __restrict__ HW1f,
    unsigned char* __restrict__ hids,
    float* __restrict__ out)
{
    cg::grid_group grid = cg::this_grid();

    __shared__ unsigned lh[NHEADS];
    __shared__ unsigned wsum[4];
    __shared__ unsigned stotal[NHEADS];
    __shared__ unsigned cumblk[NHEADS + 1];
    __shared__ unsigned lcur[NHEADS];
    __shared__ float    sW1[3 * D1];
    __shared__ __bf16   T[4][32 * 64];

    int bid = blockIdx.x;
    int G   = gridDim.x;
    int t   = threadIdx.x;
    int lane = t & 63, wv = t >> 6;

    // phase 1: hist + hids + weight conversion (grid-stride)
    for (int cb = bid; cb < NBLK_IN; cb += G)
        hist_body(cb, t, n, l, m, block_counts, hids, W2, HW1, W2f, HW1f, lh);
    grid.sync();

    // phase 2: scan (blocks 0..30)
    scan_body(bid, t, block_counts, block_off, counts, starts, block_head,
              wsum, stotal, cumblk);
    grid.sync();

    // phase 3: scatter (perm only; grid-stride)
    for (int cb = bid; cb < NBLK_IN; cb += G)
        scatter_body(cb, t, hids, starts, block_off, perm, nullptr, false, lcur);
    grid.sync();

    // phase 4: main compute, direct scatter-out (grid-stride over tiles)
    for (int i = t; i < 3 * D1; i += BLK) {
        float v = (i < 2 * D1) ? W1[i] : b1[i - 2 * D1];
        sW1[i] = v * TANH_K;
    }
    __syncthreads();
    __bf16* Tw = T[wv];

    for (int mb = bid; mb < MAX_MB; mb += G) {
        int h = block_head[mb];
        if (h < 0) continue;
        h = __builtin_amdgcn_readfirstlane(h);

        int slot = mb * SB + wv * 32 + (lane & 31);
        bool valid = (unsigned)(slot - starts[h]) < counts[h];
        int gi = 0;
        float x0 = 0.f, x1 = 0.f;
        if (valid) {
            gi = perm[slot];
            x0 = x[gi * 2];
            x1 = x[gi * 2 + 1];
        }
        float o0, o1;
        tile_compute(x0, x1, h, lane, b2, Hb1, HW2, Hb2, W2f, HW1f, sW1, Tw, o0, o1);
        if (valid && lane < 32) {
            float2 ov = {o0, o1};
            reinterpret_cast<float2*>(out)[gi] = ov;
        }
        // WAR fence: this wave's Tw reads done before next tile overwrites
        asm volatile("s_waitcnt lgkmcnt(0)" ::: "memory");
    }
}

// ================= fallback multi-kernel path (round-9 proven) =================
__global__ __launch_bounds__(BLK) void k_hist(const int* __restrict__ n,
                                              const int* __restrict__ l,
                                              const int* __restrict__ m,
                                              unsigned* __restrict__ block_counts,
                                              unsigned char* __restrict__ hids,
                                              const float* __restrict__ W2,
                                              const float* __restrict__ HW1,
                                              __bf16* __restrict__ W2f,
                                              __bf16* __restrict__ HW1f) {
    __shared__ unsigned lh[NHEADS];
    hist_body(blockIdx.x, threadIdx.x, n, l, m, block_counts, hids, W2, HW1, W2f, HW1f, lh);
}

__global__ __launch_bounds__(BLK) void k_scan(const unsigned* __restrict__ block_counts,
                                              unsigned* __restrict__ block_off,
                                              unsigned* __restrict__ counts,
                                              unsigned* __restrict__ starts,
                                              int* __restrict__ block_head) {
    __shared__ unsigned wsum[4];
    __shared__ unsigned stotal[NHEADS];
    __shared__ unsigned cumblk[NHEADS + 1];
    scan_body(blockIdx.x, threadIdx.x, block_counts, block_off, counts, starts,
              block_head, wsum, stotal, cumblk);
}

__global__ __launch_bounds__(BLK) void k_scatter(const unsigned char* __restrict__ hids,
                                                 const unsigned* __restrict__ starts,
                                                 const unsigned* __restrict__ block_off,
                                                 int* __restrict__ perm,
                                                 int* __restrict__ inv) {
    __shared__ unsigned lcur[NHEADS];
    scatter_body(blockIdx.x, threadIdx.x, hids, starts, block_off, perm, inv, true, lcur);
}

__global__ __launch_bounds__(BLK) void k_main(
    const float* __restrict__ x,
    const float* __restrict__ W1, const float* __restrict__ b1,
    const float* __restrict__ b2,
    const float* __restrict__ Hb1, const float* __restrict__ HW2,
    const float* __restrict__ Hb2,
    const __bf16* __restrict__ W2f, const __bf16* __restrict__ HW1f,
    const int* __restrict__ block_head, const int* __restrict__ perm,
    const unsigned* __restrict__ starts, const unsigned* __restrict__ counts,
    float* __restrict__ temp)
{
    int h = block_head[blockIdx.x];
    if (h < 0) return;
    h = __builtin_amdgcn_readfirstlane(h);

    __shared__ float  sW1[3 * D1];
    __shared__ __bf16 T[4][32 * 64];

    int t = threadIdx.x;
    for (int i = t; i < 3 * D1; i += BLK) {
        float v = (i < 2 * D1) ? W1[i] : b1[i - 2 * D1];
        sW1[i] = v * TANH_K;
    }
    __syncthreads();

    int lane = t & 63, wv = t >> 6;
    int slot = blockIdx.x * SB + wv * 32 + (lane & 31);
    bool valid = (unsigned)(slot - starts[h]) < counts[h];
    float x0 = 0.f, x1 = 0.f;
    if (valid) {
        int gi = perm[slot];
        x0 = x[gi * 2];
        x1 = x[gi * 2 + 1];
    }
    float o0, o1;
    tile_compute(x0, x1, h, lane, b2, Hb1, HW2, Hb2, W2f, HW1f, sW1, T[wv], o0, o1);
    if (lane < 32) {
        float2 ov = {o0, o1};
        reinterpret_cast<float2*>(temp)[slot] = ov;
    }
}

__global__ __launch_bounds__(BLK) void k_unperm(const int* __restrict__ inv,
                                                const float* __restrict__ temp,
                                                float* __restrict__ out) {
    int i = blockIdx.x * BLK + threadIdx.x;
    int pos = inv[i];
    float2 v = reinterpret_cast<const float2*>(temp)[pos];
    reinterpret_cast<float2*>(out)[i] = v;
}

extern "C" void kernel_launch(void* const* d_in, const int* in_sizes, int n_in,
                              void* d_out, int out_size, void* d_ws, size_t ws_size,
                              hipStream_t stream) {
    const float* x   = (const float*)d_in[0];
    const int*   n   = (const int*)d_in[1];
    const int*   l   = (const int*)d_in[2];
    const int*   m   = (const int*)d_in[3];
    const float* W1  = (const float*)d_in[4];
    const float* b1  = (const float*)d_in[5];
    const float* W2  = (const float*)d_in[6];
    const float* b2  = (const float*)d_in[7];
    const float* HW1 = (const float*)d_in[8];
    const float* Hb1 = (const float*)d_in[9];
    const float* HW2 = (const float*)d_in[10];
    const float* Hb2 = (const float*)d_in[11];
    float* out = (float*)d_out;

    char* ws = (char*)d_ws;
    unsigned* counts       = (unsigned*)(ws + 0);
    unsigned* starts       = (unsigned*)(ws + 128);
    int*      block_head   = (int*)(ws + 512);
    unsigned* block_counts = (unsigned*)(ws + 16384);
    unsigned* block_off    = (unsigned*)(ws + 139264);
    int*      perm         = (int*)(ws + 270336);
    int*      inv          = (int*)(ws + 1349632);
    float*    temp         = (float*)(ws + 2400256);
    __bf16*   W2f          = (__bf16*)(ws + 4558848);
    __bf16*   HW1f         = (__bf16*)(ws + 4575232);
    unsigned char* hids    = (unsigned char*)(ws + 4700160);

    // attempt cooperative fused launch with runtime-validated grid size
    int maxActive = 0;
    hipError_t qerr = hipOccupancyMaxActiveBlocksPerMultiprocessor(
        &maxActive, (const void*)k_fused, BLK, 0);
    int G = maxActive * 256;               // 256 CUs on MI355X
    if (G > GRID_MAX) G = GRID_MAX;

    if (qerr == hipSuccess && G >= 256) {
        void* args[] = {
            (void*)&x, (void*)&n, (void*)&l, (void*)&m,
            (void*)&W1, (void*)&b1, (void*)&W2, (void*)&b2,
            (void*)&HW1, (void*)&Hb1, (void*)&HW2, (void*)&Hb2,
            (void*)&counts, (void*)&starts, (void*)&block_head,
            (void*)&block_counts, (void*)&block_off, (void*)&perm,
            (void*)&W2f, (void*)&HW1f, (void*)&hids, (void*)&out
        };
        hipError_t lerr = hipLaunchCooperativeKernel((void*)k_fused, dim3(G), dim3(BLK),
                                                     args, 0, stream);
        if (lerr == hipSuccess) return;
    }

    // fallback: proven 5-kernel pipeline
    k_hist   <<<NBLK_IN, BLK, 0, stream>>>(n, l, m, block_counts, hids, W2, HW1, W2f, HW1f);
    k_scan   <<<NHEADS + 1, BLK, 0, stream>>>(block_counts, block_off, counts, starts, block_head);
    k_scatter<<<NBLK_IN, BLK, 0, stream>>>(hids, starts, block_off, perm, inv);
    k_main   <<<MAX_MB, BLK, 0, stream>>>(x, W1, b1, b2, Hb1, HW2, Hb2,
                                          W2f, HW1f, block_head, perm,
                                          starts, counts, temp);
    k_unperm <<<NBLK_IN, BLK, 0, stream>>>(inv, temp, out);
}

// Round 13
// 46.133 us; speedup vs baseline: 5.0868x; 5.0868x over previous
//
#include <hip/hip_runtime.h>
#include <hip/hip_bf16.h>
#include <math.h>

#define B_TOTAL 262144
#define NHEADS  30
#define D1      128
#define D2      64
#define DH      32
#define BLK     256
#define NBLK_IN (B_TOTAL / BLK)            // 1024 input chunks (256 samples each)
#define SB      128                        // slots per k_main block
#define MAX_MB  (B_TOTAL / SB + NHEADS)    // 2078 main blocks

#define TANH_K  2.885390081777927f         // 2/ln2: tanh(v)=1-2/(exp2(K v)+1)

typedef __attribute__((ext_vector_type(8))) __bf16 bf16x8;
typedef __attribute__((ext_vector_type(4))) float  f32x4;

// ---------------- ws layout (bytes) ----------------
// 0        counts[30] u32            (written by k_scan block 30)
// 128      starts[30] u32            (slot units, multiples of 128)
// 512      block_head[MAX_MB] i32
// 16384    block_counts[30][1024] u32  (transposed)
// 139264   block_off[30][1024] u32     (transposed)
// 270336   perm[MAX_MB*SB] i32       (no init; guarded by counts)
// 4558848  W2f  bf16[8192]           (fragment-ordered, pre-scaled by TANH_K)
// 4575232  HW1f bf16[30*2048]        (fragment-ordered, pre-scaled by TANH_K)
// 4700160  hids u8[B_TOTAL]

__device__ __forceinline__ int head_id(int nn, int ll, int mm) {
    return (nn - 1) * nn * (2 * nn - 1) / 6 + ll * ll + (mm + ll);
}

// input u is already pre-scaled by TANH_K: tanh = 1 - 2*rcp(exp2(u)+1)
__device__ __forceinline__ float tanh_pre(float u) {
    float e = __builtin_amdgcn_exp2f(u);
    return 1.0f - 2.0f * __builtin_amdgcn_rcpf(e + 1.0f);
}

// hist (all blocks) + hid cache + one-time weight conversion (first 272 blocks)
__global__ __launch_bounds__(BLK) void k_hist(const int* __restrict__ n,
                                              const int* __restrict__ l,
                                              const int* __restrict__ m,
                                              unsigned* __restrict__ block_counts,
                                              unsigned char* __restrict__ hids,
                                              const float* __restrict__ W2,
                                              const float* __restrict__ HW1,
                                              __bf16* __restrict__ W2f,
                                              __bf16* __restrict__ HW1f) {
    __shared__ unsigned lh[NHEADS];
    int t = threadIdx.x;
    if (t < NHEADS) lh[t] = 0u;
    __syncthreads();
    int i = blockIdx.x * BLK + t;
    int hid = head_id(n[i], l[i], m[i]);
    hids[i] = (unsigned char)hid;
    atomicAdd(&lh[hid], 1u);

    if (blockIdx.x < 272) {                  // fused weight conversion (pre-scaled)
        int idx = blockIdx.x * BLK + t;
        if (idx < 8192) {
            int jj = idx & 7, ln = (idx >> 3) & 63, nt = (idx >> 9) & 3, kt = (idx >> 11) & 3;
            int k = kt * 32 + (ln >> 4) * 8 + jj;
            int c = nt * 16 + (ln & 15);
            W2f[idx] = (__bf16)(W2[k * D2 + c] * TANH_K);
        } else {
            int id2 = idx - 8192;            // < 61440
            int jj = id2 & 7, ln = (id2 >> 3) & 63;
            int nt2 = (id2 >> 9) & 1, kt2 = (id2 >> 10) & 1, h = id2 >> 11;
            int k = kt2 * 32 + (ln >> 4) * 8 + jj;
            int c = nt2 * 16 + (ln & 15);
            HW1f[h * 2048 + ((kt2 * 2 + nt2) * 64 + ln) * 8 + jj] =
                (__bf16)(HW1[h * (D2 * DH) + k * DH + c] * TANH_K);
        }
    }

    __syncthreads();
    if (t < NHEADS) block_counts[t * NBLK_IN + blockIdx.x] = lh[t];   // transposed
}

// blocks 0..29: coalesced single-pass scan of one head's 1024 counts.
// block 30: computes head totals itself (redundant sum), then starts/block_head.
__global__ __launch_bounds__(BLK) void k_scan(const unsigned* __restrict__ block_counts,
                                              unsigned* __restrict__ block_off,
                                              unsigned* __restrict__ counts,
                                              unsigned* __restrict__ starts,
                                              int* __restrict__ block_head) {
    int h = blockIdx.x;
    int t = threadIdx.x;
    if (h < NHEADS) {
        __shared__ unsigned wsum[4];
        int lane = t & 63, wv = t >> 6;
        uint4 v = reinterpret_cast<const uint4*>(block_counts + h * NBLK_IN)[t];
        unsigned tsum = v.x + v.y + v.z + v.w;
        unsigned s = tsum;
        #pragma unroll
        for (int d = 1; d < 64; d <<= 1) {
            unsigned u = __shfl_up(s, d, 64);
            if (lane >= d) s += u;
        }
        if (lane == 63) wsum[wv] = s;
        __syncthreads();
        unsigned woff = 0;
        #pragma unroll
        for (int w = 0; w < 3; ++w) woff += (w < wv) ? wsum[w] : 0u;
        unsigned ex = woff + s - tsum;       // exclusive prefix for this thread
        uint4 o;
        o.x = ex;
        o.y = ex + v.x;
        o.z = ex + v.x + v.y;
        o.w = ex + v.x + v.y + v.z;
        reinterpret_cast<uint4*>(block_off + h * NBLK_IN)[t] = o;
    } else {
        __shared__ unsigned stotal[NHEADS];
        __shared__ unsigned cumblk[NHEADS + 1];
        int lane = t & 63, wv = t >> 6;
        for (int hh = wv; hh < NHEADS; hh += 4) {
            const uint4* p = reinterpret_cast<const uint4*>(block_counts + hh * NBLK_IN);
            unsigned sum = 0;
            #pragma unroll
            for (int c = 0; c < 4; ++c) {
                uint4 v = p[lane + c * 64];
                sum += v.x + v.y + v.z + v.w;
            }
            #pragma unroll
            for (int d = 32; d >= 1; d >>= 1) sum += __shfl_down(sum, d, 64);
            if (lane == 0) { stotal[hh] = sum; counts[hh] = sum; }
        }
        __syncthreads();
        if (t == 0) {
            unsigned tb = 0;
            for (int hh = 0; hh < NHEADS; ++hh) {
                starts[hh] = tb * SB;
                cumblk[hh] = tb;
                tb += (stotal[hh] + SB - 1) / SB;
            }
            cumblk[NHEADS] = tb;
        }
        __syncthreads();
        unsigned tb = cumblk[NHEADS];
        for (int b = t; b < MAX_MB; b += BLK) {
            int hh = -1;
            if ((unsigned)b < tb) {
                hh = 0;
                while (cumblk[hh + 1] <= (unsigned)b) ++hh;
            }
            block_head[b] = hh;
        }
    }
}

__global__ __launch_bounds__(BLK) void k_scatter(const unsigned char* __restrict__ hids,
                                                 const unsigned* __restrict__ starts,
                                                 const unsigned* __restrict__ block_off,
                                                 int* __restrict__ perm) {
    __shared__ unsigned lcur[NHEADS];
    int t = threadIdx.x;
    if (t < NHEADS) lcur[t] = 0u;
    __syncthreads();
    int i = blockIdx.x * BLK + t;
    int hid = hids[i];
    unsigned rank = atomicAdd(&lcur[hid], 1u);
    unsigned pos = starts[hid] + block_off[hid * NBLK_IN + blockIdx.x] + rank;
    perm[pos] = i;
}

// each wave owns 32 samples (rows); block = 4 waves = 128 slots; direct scatter-out
__global__ __launch_bounds__(BLK) void k_main(
    const float* __restrict__ x,
    const float* __restrict__ W1, const float* __restrict__ b1,
    const float* __restrict__ b2,
    const float* __restrict__ Hb1, const float* __restrict__ HW2,
    const float* __restrict__ Hb2,
    const __bf16* __restrict__ W2f, const __bf16* __restrict__ HW1f,
    const int* __restrict__ block_head, const int* __restrict__ perm,
    const unsigned* __restrict__ starts, const unsigned* __restrict__ counts,
    float* __restrict__ out)
{
    int h = block_head[blockIdx.x];
    if (h < 0) return;
    h = __builtin_amdgcn_readfirstlane(h);

    __shared__ float  sW1[3 * D1];          // K*w0 | K*w1 | K*b1  (1.5 KB)
    __shared__ __bf16 T[4][32 * 64];        // per-wave 32 rows x 64 cols (16 KB)

    int t = threadIdx.x;
    for (int i = t; i < 3 * D1; i += BLK) {
        float v = (i < 2 * D1) ? W1[i] : b1[i - 2 * D1];
        sW1[i] = v * TANH_K;                // pre-scale layer-1 tanh inputs
    }
    __syncthreads();                        // only barrier in the kernel

    int lane = t & 63, wv = t >> 6;
    int kgrp = lane >> 4;                   // 0..3
    int lid  = lane & 15;
    int row  = lane & 31;                   // sample row (lanes 32-63 duplicate)
    int slot = blockIdx.x * SB + wv * 32 + row;
    bool valid = (unsigned)(slot - starts[h]) < counts[h];
    int gi = 0;
    float x0 = 0.f, x1 = 0.f;
    if (valid) {
        gi = perm[slot];
        x0 = x[gi * 2];
        x1 = x[gi * 2 + 1];
    }

    // x for the 2 m-tiles this wave owns (rows tm*16 + lid, held by lanes 0..31)
    float xs0[2], xs1[2];
    #pragma unroll
    for (int tm = 0; tm < 2; ++tm) {
        int src = tm * 16 + lid;
        xs0[tm] = __shfl(x0, src, 64);
        xs1[tm] = __shfl(x1, src, 64);
    }

    // ---- layer 2 GEMM: [32x128]x[128x64] per wave, acc init = K*b2 ----
    f32x4 acc2[2][4];
    #pragma unroll
    for (int nt = 0; nt < 4; ++nt) {
        float bv = b2[nt * 16 + lid] * TANH_K;
        f32x4 c4 = {bv, bv, bv, bv};
        acc2[0][nt] = c4;
        acc2[1][nt] = c4;
    }

    #pragma unroll
    for (int kt = 0; kt < 4; ++kt) {
        int jb = kt * 32 + kgrp * 8;
        float4 w0a = *(const float4*)&sW1[jb];
        float4 w0b = *(const float4*)&sW1[jb + 4];
        float4 w1a = *(const float4*)&sW1[D1 + jb];
        float4 w1b = *(const float4*)&sW1[D1 + jb + 4];
        float4 bba = *(const float4*)&sW1[2 * D1 + jb];
        float4 bbb = *(const float4*)&sW1[2 * D1 + jb + 4];
        float w0[8] = {w0a.x, w0a.y, w0a.z, w0a.w, w0b.x, w0b.y, w0b.z, w0b.w};
        float w1[8] = {w1a.x, w1a.y, w1a.z, w1a.w, w1b.x, w1b.y, w1b.z, w1b.w};
        float bb[8] = {bba.x, bba.y, bba.z, bba.w, bbb.x, bbb.y, bbb.z, bbb.w};
        bf16x8 a1[2];
        #pragma unroll
        for (int tm = 0; tm < 2; ++tm)
            #pragma unroll
            for (int jj = 0; jj < 8; ++jj) {
                float v = tanh_pre(fmaf(xs1[tm], w1[jj], fmaf(xs0[tm], w0[jj], bb[jj])));
                a1[tm][jj] = (__bf16)v;
            }
        #pragma unroll
        for (int nt = 0; nt < 4; ++nt) {
            bf16x8 bfr = *reinterpret_cast<const bf16x8*>(W2f + ((kt * 4 + nt) * 64 + lane) * 8);
            #pragma unroll
            for (int tm = 0; tm < 2; ++tm)
                acc2[tm][nt] = __builtin_amdgcn_mfma_f32_16x16x32_bf16(a1[tm], bfr, acc2[tm][nt], 0, 0, 0);
        }
    }

    // ---- h2 = tanh(acc2) -> Tw cols 0..63 (swizzled: chunk = (c>>3)^(r&7)) ----
    __bf16* Tw = T[wv];
    #pragma unroll
    for (int tm = 0; tm < 2; ++tm)
        #pragma unroll
        for (int nt = 0; nt < 4; ++nt)
            #pragma unroll
            for (int rg = 0; rg < 4; ++rg) {
                int r = tm * 16 + kgrp * 4 + rg;          // 0..31
                int c = nt * 16 + lid;                    // 0..63
                int chunk = (c >> 3) ^ (r & 7);
                Tw[r * 64 + chunk * 8 + (c & 7)] = (__bf16)tanh_pre(acc2[tm][nt][rg]);
            }

    // ---- head layer 1 GEMM: [32x64]x[64x32], acc init = K*Hb1 ----
    f32x4 acc3[2][2];
    #pragma unroll
    for (int nt = 0; nt < 2; ++nt) {
        float bv = Hb1[h * DH + nt * 16 + lid] * TANH_K;
        f32x4 c4 = {bv, bv, bv, bv};
        acc3[0][nt] = c4;
        acc3[1][nt] = c4;
    }
    #pragma unroll
    for (int kt2 = 0; kt2 < 2; ++kt2) {
        #pragma unroll
        for (int tm = 0; tm < 2; ++tm) {
            int r = tm * 16 + lid;
            int chunk = (kt2 * 4 + kgrp) ^ (r & 7);
            bf16x8 a2v = *reinterpret_cast<const bf16x8*>(&Tw[r * 64 + chunk * 8]);
            #pragma unroll
            for (int nt3 = 0; nt3 < 2; ++nt3) {
                bf16x8 bfr = *reinterpret_cast<const bf16x8*>(HW1f + h * 2048 + ((kt2 * 2 + nt3) * 64 + lane) * 8);
                acc3[tm][nt3] = __builtin_amdgcn_mfma_f32_16x16x32_bf16(a2v, bfr, acc3[tm][nt3], 0, 0, 0);
            }
        }
    }

    // ---- z = tanh(acc3) -> Tw cols 32..63 (h2 reads precede in program order) ----
    #pragma unroll
    for (int tm = 0; tm < 2; ++tm)
        #pragma unroll
        for (int nt3 = 0; nt3 < 2; ++nt3)
            #pragma unroll
            for (int rg = 0; rg < 4; ++rg) {
                int r = tm * 16 + kgrp * 4 + rg;          // 0..31
                int c = 32 + nt3 * 16 + lid;              // 32..63
                int chunk = (c >> 3) ^ (r & 7);
                Tw[r * 64 + chunk * 8 + (c & 7)] = (__bf16)tanh_pre(acc3[tm][nt3][rg]);
            }

    // ---- head layer 2 (VALU, uniform s_load weights); accumulate per chunk ----
    const float* hw2 = HW2 + h * DH * 2;
    float o0 = Hb2[h * 2], o1 = Hb2[h * 2 + 1];
    #pragma unroll
    for (int i4 = 0; i4 < 4; ++i4) {
        int chunk = (4 + i4) ^ (row & 7);                 // cols 32+8*i4 .. +7
        bf16x8 zz = *reinterpret_cast<const bf16x8*>(&Tw[row * 64 + chunk * 8]);
        #pragma unroll
        for (int jj = 0; jj < 8; ++jj) {
            float zv = (float)zz[jj];
            int j = i4 * 8 + jj;
            o0 = fmaf(zv, hw2[2 * j], o0);
            o1 = fmaf(zv, hw2[2 * j + 1], o1);
        }
    }
    if (valid && lane < 32) {
        float2 ov = {o0, o1};
        reinterpret_cast<float2*>(out)[gi] = ov;          // direct scatter-out
    }
}

extern "C" void kernel_launch(void* const* d_in, const int* in_sizes, int n_in,
                              void* d_out, int out_size, void* d_ws, size_t ws_size,
                              hipStream_t stream) {
    const float* x   = (const float*)d_in[0];
    const int*   n   = (const int*)d_in[1];
    const int*   l   = (const int*)d_in[2];
    const int*   m   = (const int*)d_in[3];
    const float* W1  = (const float*)d_in[4];
    const float* b1  = (const float*)d_in[5];
    const float* W2  = (const float*)d_in[6];
    const float* b2  = (const float*)d_in[7];
    const float* HW1 = (const float*)d_in[8];
    const float* Hb1 = (const float*)d_in[9];
    const float* HW2 = (const float*)d_in[10];
    const float* Hb2 = (const float*)d_in[11];
    float* out = (float*)d_out;

    char* ws = (char*)d_ws;
    unsigned* counts       = (unsigned*)(ws + 0);
    unsigned* starts       = (unsigned*)(ws + 128);
    int*      block_head   = (int*)(ws + 512);
    unsigned* block_counts = (unsigned*)(ws + 16384);
    unsigned* block_off    = (unsigned*)(ws + 139264);
    int*      perm         = (int*)(ws + 270336);
    __bf16*   W2f          = (__bf16*)(ws + 4558848);
    __bf16*   HW1f         = (__bf16*)(ws + 4575232);
    unsigned char* hids    = (unsigned char*)(ws + 4700160);

    k_hist   <<<NBLK_IN, BLK, 0, stream>>>(n, l, m, block_counts, hids, W2, HW1, W2f, HW1f);
    k_scan   <<<NHEADS + 1, BLK, 0, stream>>>(block_counts, block_off, counts, starts, block_head);
    k_scatter<<<NBLK_IN, BLK, 0, stream>>>(hids, starts, block_off, perm);
    k_main   <<<MAX_MB, BLK, 0, stream>>>(x, W1, b1, b2, Hb1, HW2, Hb2,
                                          W2f, HW1f, block_head, perm,
                                          starts, counts, out);
}